// Round 1
// baseline (383.513 us; speedup 1.0000x reference)
//
#include <hip/hip_runtime.h>
#include <stdint.h>

typedef unsigned long long u64;

#define CHUNK 2048      // elements per LDS sort chunk
#define CTHREADS 1024   // threads per chunk block (2 elems/thread)
#define NSEG 1024       // parallel PAVA segments

__device__ __forceinline__ void cmpswap(u64& a, u64& b, bool desc) {
  bool sw = desc ? (a < b) : (a > b);
  if (sw) { u64 t = a; a = b; b = t; }
}

// Build composite keys: (bits(|u-x|) << 32) | ~index  -> descending u64 sort
// == stable argsort(-abs). Pad with 0 (all real keys > 0 since ~idx > 0).
__global__ void k_init(const float* __restrict__ u, const float* __restrict__ x,
                       u64* __restrict__ key, int n, int npad) {
  int t = blockIdx.x * blockDim.x + threadIdx.x;
  if (t >= npad) return;
  if (t < n) {
    float d = u[t] - x[t];
    unsigned ab = __float_as_uint(fabsf(d));
    key[t] = ((u64)ab << 32) | (unsigned)(~(unsigned)t);
  } else {
    key[t] = 0ull;
  }
}

// Full bitonic sort of each 2048-chunk in LDS (stages k=2..2048).
// Direction from GLOBAL index so chunks alternate for the outer merge stages.
__global__ void k_sort_chunk(u64* __restrict__ key) {
  __shared__ u64 s[CHUNK];
  int base = blockIdx.x * CHUNK;
  s[threadIdx.x] = key[base + threadIdx.x];
  s[threadIdx.x + CTHREADS] = key[base + threadIdx.x + CTHREADS];
  __syncthreads();
  for (int k = 2; k <= CHUNK; k <<= 1) {
    for (int j = k >> 1; j > 0; j >>= 1) {
      int t = threadIdx.x;
      int i = 2 * t - (t & (j - 1));
      bool desc = (((base + i) & k) == 0);
      cmpswap(s[i], s[i + j], desc);
      __syncthreads();
    }
  }
  key[base + threadIdx.x] = s[threadIdx.x];
  key[base + threadIdx.x + CTHREADS] = s[threadIdx.x + CTHREADS];
}

// One global compare-exchange pass (j >= CHUNK).
__global__ void k_merge_global(u64* __restrict__ key, int k, int j) {
  int t = blockIdx.x * blockDim.x + threadIdx.x;
  int i = 2 * t - (t & (j - 1));
  bool desc = ((i & k) == 0);
  u64 a = key[i], b = key[i + j];
  bool sw = desc ? (a < b) : (a > b);
  if (sw) { key[i] = b; key[i + j] = a; }
}

// Fused j = 1024..1 passes of stage k, per 2048-chunk in LDS.
__global__ void k_merge_shared(u64* __restrict__ key, int k) {
  __shared__ u64 s[CHUNK];
  int base = blockIdx.x * CHUNK;
  s[threadIdx.x] = key[base + threadIdx.x];
  s[threadIdx.x + CTHREADS] = key[base + threadIdx.x + CTHREADS];
  __syncthreads();
  for (int j = CHUNK >> 1; j > 0; j >>= 1) {
    int t = threadIdx.x;
    int i = 2 * t - (t & (j - 1));
    bool desc = (((base + i) & k) == 0);
    cmpswap(s[i], s[i + j], desc);
    __syncthreads();
  }
  key[base + threadIdx.x] = s[threadIdx.x];
  key[base + threadIdx.x + CTHREADS] = s[threadIdx.x + CTHREADS];
}

// Per-thread sequential PAVA (non-increasing fit) on segment [tid*Lc, ...).
// iso_in[r] = |diff| (recovered from key's high bits) - w[r].
// Emits pools as linked list: sum/cnt at pool-start rank, cnt=0 elsewhere.
__global__ void k_pava_seg(const u64* __restrict__ key, const float* __restrict__ w,
                           float* __restrict__ stkSum, float* __restrict__ stkCnt,
                           float* __restrict__ pSum, float* __restrict__ pCnt,
                           int* __restrict__ prv, int* __restrict__ nxt,
                           int* __restrict__ headB, int* __restrict__ tailB,
                           int n, int Lc) {
  int tid = blockIdx.x * blockDim.x + threadIdx.x;
  if (tid >= NSEG) return;
  int s = tid * Lc;
  int e = min(s + Lc, n);
  if (s >= e) { headB[tid] = -1; tailB[tid] = -1; return; }
  float ts = 0.f, tc = 0.f;   // top-of-stack pool in registers
  int depth = 0;              // pools spilled to stk arrays (segment-private slice)
  for (int r = s; r < e; ++r) {
    u64 kk = key[r];
    float a = __uint_as_float((unsigned)(kk >> 32));
    float yv = a - w[r];
    if (r > s) { stkSum[s + depth] = ts; stkCnt[s + depth] = tc; ++depth; }
    ts = yv; tc = 1.f;
    // merge while mean(top) > mean(prev)  (strict, matches reference on -y)
    while (depth > 0) {
      float ps = stkSum[s + depth - 1];
      float pc = stkCnt[s + depth - 1];
      if (ts * pc > ps * tc) { ts += ps; tc += pc; --depth; }
      else break;
    }
  }
  // emit pools in order; pool j starts at cumulative-count offset
  int prevStart = -1;
  int start = s;
  for (int j = 0; j <= depth; ++j) {
    float sj = (j < depth) ? stkSum[s + j] : ts;
    float cj = (j < depth) ? stkCnt[s + j] : tc;
    pSum[start] = sj;
    pCnt[start] = cj;
    prv[start] = prevStart;
    if (prevStart >= 0) nxt[prevStart] = start;
    int c = (int)cj;
    for (int z = 1; z < c; ++z) pCnt[start + z] = 0.f;
    prevStart = start;
    start += c;
  }
  nxt[prevStart] = -1;
  headB[tid] = s;
  tailB[tid] = prevStart;
}

// Hierarchical pairwise segment merge, 10 rounds in one block.
// Junction cascade: grow the merged pool absorbing left (prev) while
// mean(cur) > mean(prev), and right (next) while mean(next) > mean(cur).
// PAVA's fixed point is order-invariant, so this is exact.
__global__ void k_merge_pools(float* __restrict__ pSum, float* __restrict__ pCnt,
                              int* __restrict__ prv, int* __restrict__ nxt,
                              int* __restrict__ headB, int* __restrict__ tailB) {
  for (int step = 1; step < NSEG; step <<= 1) {
    int pairs = NSEG / (2 * step);
    int t = threadIdx.x;
    if (t < pairs) {
      int sL = t * 2 * step;
      int sR = sL + step;
      int hR = headB[sR];
      if (hR >= 0) {
        if (headB[sL] < 0) {
          headB[sL] = hR; tailB[sL] = tailB[sR];
        } else {
          int l = tailB[sL];
          int r = hR;
          nxt[l] = r; prv[r] = l;
          int cur = r;
          for (;;) {
            int p = prv[cur];
            if (p >= 0 && pSum[cur] * pCnt[p] > pSum[p] * pCnt[cur]) {
              pSum[p] += pSum[cur];
              pCnt[p] += pCnt[cur];
              pCnt[cur] = 0.f;
              int nx = nxt[cur];
              nxt[p] = nx;
              if (nx >= 0) prv[nx] = p;
              cur = p;
              continue;
            }
            int nx = nxt[cur];
            if (nx >= 0 && pSum[nx] * pCnt[cur] > pSum[cur] * pCnt[nx]) {
              pSum[cur] += pSum[nx];
              pCnt[cur] += pCnt[nx];
              pCnt[nx] = 0.f;
              int nn = nxt[nx];
              nxt[cur] = nn;
              if (nn >= 0) prv[nn] = cur;
              continue;
            }
            break;
          }
          int tR = tailB[sR];
          tailB[sL] = (pCnt[tR] > 0.f) ? tR : cur;
        }
      }
    }
    __syncthreads();
  }
}

// Each active pool start writes clipped mean to its covered ranks;
// recover original index from key low bits, apply sign, add x.
__global__ void k_scatter(const u64* __restrict__ key,
                          const float* __restrict__ pSum, const float* __restrict__ pCnt,
                          const float* __restrict__ u, const float* __restrict__ x,
                          float* __restrict__ out, int n) {
  int i = blockIdx.x * blockDim.x + threadIdx.x;
  if (i >= n) return;
  float c = pCnt[i];
  if (c > 0.f) {
    float m = fmaxf(pSum[i] / c, 0.f);
    int e = i + (int)c;
    for (int k = i; k < e; ++k) {
      unsigned idx = ~(unsigned)(key[k] & 0xFFFFFFFFull);
      float d = u[idx] - x[idx];
      float v = (d > 0.f) ? m : ((d < 0.f) ? -m : 0.f);
      out[idx] = x[idx] + v;
    }
  }
}

extern "C" void kernel_launch(void* const* d_in, const int* in_sizes, int n_in,
                              void* d_out, int out_size, void* d_ws, size_t ws_size,
                              hipStream_t stream) {
  const float* u = (const float*)d_in[0];
  const float* x = (const float*)d_in[1];
  const float* w = (const float*)d_in[2];
  float* out = (float*)d_out;
  int n = in_sizes[0];          // 150528
  int npad = CHUNK;
  while (npad < n) npad <<= 1;  // 262144

  // workspace carve (~5.7 MB total)
  char* base = (char*)d_ws;
  u64* key   = (u64*)base;   base += (size_t)npad * 8;
  float* stkSum = (float*)base; base += (size_t)n * 4;
  float* stkCnt = (float*)base; base += (size_t)n * 4;
  float* pSum   = (float*)base; base += (size_t)n * 4;
  float* pCnt   = (float*)base; base += (size_t)n * 4;
  int* prv   = (int*)base;   base += (size_t)n * 4;
  int* nxt   = (int*)base;   base += (size_t)n * 4;
  int* headB = (int*)base;   base += (size_t)NSEG * 4;
  int* tailB = (int*)base;   base += (size_t)NSEG * 4;

  hipLaunchKernelGGL(k_init, dim3((npad + 255) / 256), dim3(256), 0, stream,
                     u, x, key, n, npad);

  int nchunks = npad / CHUNK;
  hipLaunchKernelGGL(k_sort_chunk, dim3(nchunks), dim3(CTHREADS), 0, stream, key);
  for (int k = CHUNK * 2; k <= npad; k <<= 1) {
    for (int j = k >> 1; j >= CHUNK; j >>= 1) {
      hipLaunchKernelGGL(k_merge_global, dim3(npad / 2 / 256), dim3(256), 0, stream,
                         key, k, j);
    }
    hipLaunchKernelGGL(k_merge_shared, dim3(nchunks), dim3(CTHREADS), 0, stream, key, k);
  }

  int Lc = (n + NSEG - 1) / NSEG;  // 147
  hipLaunchKernelGGL(k_pava_seg, dim3(NSEG / 64), dim3(64), 0, stream,
                     key, w, stkSum, stkCnt, pSum, pCnt, prv, nxt, headB, tailB, n, Lc);
  hipLaunchKernelGGL(k_merge_pools, dim3(1), dim3(512), 0, stream,
                     pSum, pCnt, prv, nxt, headB, tailB);
  hipLaunchKernelGGL(k_scatter, dim3((n + 255) / 256), dim3(256), 0, stream,
                     key, pSum, pCnt, u, x, out, n);
}

// Round 3
// 273.126 us; speedup vs baseline: 1.4042x; 1.4042x over previous
//
#include <hip/hip_runtime.h>
#include <stdint.h>

typedef unsigned long long u64;

#define CHUNK 2048      // elements per LDS sort chunk
#define CTHREADS 1024   // threads per chunk block (2 elems/thread)
#define LOG_CHUNK 11
#define NSEG 8192       // parallel PAVA segments

__device__ __forceinline__ void cmpswap(u64& a, u64& b, bool desc) {
  bool sw = desc ? (a < b) : (a > b);
  if (sw) { u64 t = a; a = b; b = t; }
}

// Build composite keys (bits(|u-x|)<<32 | ~idx) and fully sort each
// 2048-chunk in LDS. Descending u64 == stable argsort(-abs).
__global__ void k_sort_chunk(const float* __restrict__ u, const float* __restrict__ x,
                             u64* __restrict__ key, int n) {
  __shared__ u64 s[CHUNK];
  int base = blockIdx.x * CHUNK;
  for (int q = 0; q < 2; ++q) {
    int g = base + threadIdx.x + q * CTHREADS;
    u64 kk = 0ull;
    if (g < n) {
      float d = u[g] - x[g];
      kk = ((u64)__float_as_uint(fabsf(d)) << 32) | (unsigned)(~(unsigned)g);
    }
    s[threadIdx.x + q * CTHREADS] = kk;
  }
  __syncthreads();
  for (int k = 2; k <= CHUNK; k <<= 1) {
    for (int j = k >> 1; j > 0; j >>= 1) {
      int t = threadIdx.x;
      int i = 2 * t - (t & (j - 1));
      bool desc = (((base + i) & k) == 0);
      cmpswap(s[i], s[i + j], desc);
      __syncthreads();
    }
  }
  key[base + threadIdx.x] = s[threadIdx.x];
  key[base + threadIdx.x + CTHREADS] = s[threadIdx.x + CTHREADS];
}

// Fused NL bitonic levels (j = 2^(p_lo+NL-1) .. 2^p_lo, all >= CHUNK) of
// stage k, done in registers: 2^NL keys per thread. All fused levels sit
// below bit log2(k), so the direction is uniform within the group.
template<int NL>
__global__ void k_merge_fused(u64* __restrict__ key, int k, int p_lo) {
  int t = blockIdx.x * blockDim.x + threadIdx.x;
  int jlo = 1 << p_lo;
  int low = t & (jlo - 1);
  int base = ((t >> p_lo) << (p_lo + NL)) | low;
  bool desc = ((base & k) == 0);
  u64 v[1 << NL];
#pragma unroll
  for (int m = 0; m < (1 << NL); ++m) v[m] = key[base + m * jlo];
#pragma unroll
  for (int lev = NL - 1; lev >= 0; --lev) {
    int st = 1 << lev;
#pragma unroll
    for (int m = 0; m < (1 << NL); ++m) {
      if ((m & st) == 0) cmpswap(v[m], v[m + st], desc);
    }
  }
#pragma unroll
  for (int m = 0; m < (1 << NL); ++m) key[base + m * jlo] = v[m];
}

// Fused j = 1024..1 levels of stage k, per 2048-chunk in LDS.
__global__ void k_merge_shared(u64* __restrict__ key, int k) {
  __shared__ u64 s[CHUNK];
  int base = blockIdx.x * CHUNK;
  s[threadIdx.x] = key[base + threadIdx.x];
  s[threadIdx.x + CTHREADS] = key[base + threadIdx.x + CTHREADS];
  __syncthreads();
  for (int j = CHUNK >> 1; j > 0; j >>= 1) {
    int t = threadIdx.x;
    int i = 2 * t - (t & (j - 1));
    bool desc = (((base + i) & k) == 0);
    cmpswap(s[i], s[i + j], desc);
    __syncthreads();
  }
  key[base + threadIdx.x] = s[threadIdx.x];
  key[base + threadIdx.x + CTHREADS] = s[threadIdx.x + CTHREADS];
}

// Per-thread sequential PAVA (non-increasing fit) on segment [tid*Lc, e).
// Top AND second stack pools live in registers: the violation compare is
// pure ALU; global stack memory is only written on push (fire-and-forget)
// and re-read on an actual merge (rare). Emits pools as a linked list:
// sum/cnt at pool-start rank, cnt=0 elsewhere.
__global__ void k_pava_seg(const u64* __restrict__ key, const float* __restrict__ w,
                           float* __restrict__ stkSum, float* __restrict__ stkCnt,
                           float* __restrict__ pSum, float* __restrict__ pCnt,
                           int* __restrict__ prv, int* __restrict__ nxt,
                           int* __restrict__ headB, int* __restrict__ tailB,
                           int n, int Lc) {
  int tid = blockIdx.x * blockDim.x + threadIdx.x;
  if (tid >= NSEG) return;
  int s = tid * Lc;
  int e = min(s + Lc, n);
  if (s >= e) { headB[tid] = -1; tailB[tid] = -1; return; }
  float ts = 0.f, tc = 0.f;   // top pool
  float ss = 0.f, sc = 0.f;   // second pool (valid when depth >= 1)
  int depth = 0;              // pools below top; slots 0..depth-2 in memory
  for (int r = s; r < e; ++r) {
    u64 kk = key[r];
    float yv = __uint_as_float((unsigned)(kk >> 32)) - w[r];
    if (r > s) {
      if (depth >= 1) { stkSum[s + depth - 1] = ss; stkCnt[s + depth - 1] = sc; }
      ss = ts; sc = tc; ++depth;
    }
    ts = yv; tc = 1.f;
    // merge while mean(top) > mean(second)  (cross-multiplied, cnts > 0)
    while (depth >= 1 && ts * sc > ss * tc) {
      ts += ss; tc += sc; --depth;
      if (depth >= 1) { ss = stkSum[s + depth - 1]; sc = stkCnt[s + depth - 1]; }
    }
  }
  // emit pools bottom-to-top; pool j starts at cumulative-count offset
  int prevStart = -1;
  int start = s;
  for (int j = 0; j <= depth; ++j) {
    float sj, cj;
    if (j == depth)          { sj = ts; cj = tc; }
    else if (j == depth - 1) { sj = ss; cj = sc; }
    else                     { sj = stkSum[s + j]; cj = stkCnt[s + j]; }
    pSum[start] = sj;
    pCnt[start] = cj;
    prv[start] = prevStart;
    if (prevStart >= 0) nxt[prevStart] = start;
    int c = (int)cj;
    for (int z = 1; z < c; ++z) pCnt[start + z] = 0.f;
    prevStart = start;
    start += c;
  }
  nxt[prevStart] = -1;
  headB[tid] = s;
  tailB[tid] = prevStart;
}

// Hierarchical pairwise segment merge, log2(NSEG) rounds in one block.
// Junction cascade: absorb left while mean(cur) > mean(prev), absorb right
// while mean(next) > mean(cur). PAVA's fixed point is order-invariant.
__global__ void k_merge_pools(float* __restrict__ pSum, float* __restrict__ pCnt,
                              int* __restrict__ prv, int* __restrict__ nxt,
                              int* __restrict__ headB, int* __restrict__ tailB) {
  for (int step = 1; step < NSEG; step <<= 1) {
    int pairs = NSEG / (2 * step);
    for (int p = threadIdx.x; p < pairs; p += blockDim.x) {
      int sL = p * 2 * step;
      int sR = sL + step;
      int hR = headB[sR];
      if (hR < 0) continue;
      if (headB[sL] < 0) {
        headB[sL] = hR; tailB[sL] = tailB[sR];
        continue;
      }
      int l = tailB[sL];
      int r = hR;
      nxt[l] = r; prv[r] = l;
      int cur = r;
      for (;;) {
        int pp = prv[cur];
        if (pp >= 0 && pSum[cur] * pCnt[pp] > pSum[pp] * pCnt[cur]) {
          pSum[pp] += pSum[cur];
          pCnt[pp] += pCnt[cur];
          pCnt[cur] = 0.f;
          int nx = nxt[cur];
          nxt[pp] = nx;
          if (nx >= 0) prv[nx] = pp;
          cur = pp;
          continue;
        }
        int nx = nxt[cur];
        if (nx >= 0 && pSum[nx] * pCnt[cur] > pSum[cur] * pCnt[nx]) {
          pSum[cur] += pSum[nx];
          pCnt[cur] += pCnt[nx];
          pCnt[nx] = 0.f;
          int nn = nxt[nx];
          nxt[cur] = nn;
          if (nn >= 0) prv[nn] = cur;
          continue;
        }
        break;
      }
      int tR = tailB[sR];
      tailB[sL] = (pCnt[tR] > 0.f) ? tR : cur;
    }
    __syncthreads();
  }
}

// Each active pool start writes clipped mean to its covered ranks;
// recover original index from key low bits, apply sign, add x.
__global__ void k_scatter(const u64* __restrict__ key,
                          const float* __restrict__ pSum, const float* __restrict__ pCnt,
                          const float* __restrict__ u, const float* __restrict__ x,
                          float* __restrict__ out, int n) {
  int i = blockIdx.x * blockDim.x + threadIdx.x;
  if (i >= n) return;
  float c = pCnt[i];
  if (c > 0.f) {
    float m = fmaxf(pSum[i] / c, 0.f);
    int e = i + (int)c;
    for (int k = i; k < e; ++k) {
      unsigned idx = ~(unsigned)(key[k] & 0xFFFFFFFFull);
      float d = u[idx] - x[idx];
      float v = (d > 0.f) ? m : ((d < 0.f) ? -m : 0.f);
      out[idx] = x[idx] + v;
    }
  }
}

extern "C" void kernel_launch(void* const* d_in, const int* in_sizes, int n_in,
                              void* d_out, int out_size, void* d_ws, size_t ws_size,
                              hipStream_t stream) {
  const float* u = (const float*)d_in[0];
  const float* x = (const float*)d_in[1];
  const float* w = (const float*)d_in[2];
  float* out = (float*)d_out;
  int n = in_sizes[0];          // 150528
  int npad = CHUNK;
  while (npad < n) npad <<= 1;  // 262144

  // workspace carve (~5.7 MB total)
  char* base = (char*)d_ws;
  u64* key      = (u64*)base;   base += (size_t)npad * 8;
  float* stkSum = (float*)base; base += (size_t)(n + NSEG) * 4;
  float* stkCnt = (float*)base; base += (size_t)(n + NSEG) * 4;
  float* pSum   = (float*)base; base += (size_t)n * 4;
  float* pCnt   = (float*)base; base += (size_t)n * 4;
  int* prv   = (int*)base;   base += (size_t)n * 4;
  int* nxt   = (int*)base;   base += (size_t)n * 4;
  int* headB = (int*)base;   base += (size_t)NSEG * 4;
  int* tailB = (int*)base;   base += (size_t)NSEG * 4;

  int nchunks = npad / CHUNK;
  hipLaunchKernelGGL(k_sort_chunk, dim3(nchunks), dim3(CTHREADS), 0, stream,
                     u, x, key, n);

  for (int k = CHUNK * 2; k <= npad; k <<= 1) {
    int p_top = 31 - __builtin_clz(k) - 1;   // log2(k) - 1
    while (p_top >= LOG_CHUNK) {
      int nl = p_top - LOG_CHUNK + 1;
      if (nl > 4) nl = 4;
      int p_lo = p_top - nl + 1;
      int threads = npad >> nl;
      dim3 g(threads / 256);
      switch (nl) {
        case 1: hipLaunchKernelGGL((k_merge_fused<1>), g, dim3(256), 0, stream, key, k, p_lo); break;
        case 2: hipLaunchKernelGGL((k_merge_fused<2>), g, dim3(256), 0, stream, key, k, p_lo); break;
        case 3: hipLaunchKernelGGL((k_merge_fused<3>), g, dim3(256), 0, stream, key, k, p_lo); break;
        default: hipLaunchKernelGGL((k_merge_fused<4>), g, dim3(256), 0, stream, key, k, p_lo); break;
      }
      p_top = p_lo - 1;
    }
    hipLaunchKernelGGL(k_merge_shared, dim3(nchunks), dim3(CTHREADS), 0, stream, key, k);
  }

  int Lc = (n + NSEG - 1) / NSEG;  // 19
  hipLaunchKernelGGL(k_pava_seg, dim3(NSEG / 256), dim3(256), 0, stream,
                     key, w, stkSum, stkCnt, pSum, pCnt, prv, nxt, headB, tailB, n, Lc);
  hipLaunchKernelGGL(k_merge_pools, dim3(1), dim3(1024), 0, stream,
                     pSum, pCnt, prv, nxt, headB, tailB);
  hipLaunchKernelGGL(k_scatter, dim3((n + 255) / 256), dim3(256), 0, stream,
                     key, pSum, pCnt, u, x, out, n);
}